// Round 2
// baseline (584.584 us; speedup 1.0000x reference)
//
#include <hip/hip_runtime.h>
#include <cmath>

// ---------------------------------------------------------------------------
// GraphTransformerLayer on MI355X (gfx950).
// N=50000 nodes, C=128, H=8 heads, D=16, E=800000 edges (+N self loops).
//
// Pipeline (15 dispatches):
//   zero counts -> CSR build (count/scan x3/fill)  [edge_index is INT32!]
//   cast x -> bf16 ; transpose all weights -> bf16 [Cout][K]
//   QKV GEMMs (bf16 MFMA 16x16x32)                -> q,k,v bf16
//   k_attn: one wave per dest node, online softmax -> attn out bf16
//   Wo GEMM + bias + residual + LN1 (fused)        -> x1f fp32, x1b bf16
//   FFN1 GEMM + gelu                               -> h bf16
//   FFN2 GEMM + bias + residual + LN2 (fused)      -> d_out fp32
//
// Workspace aliasing (lifetime-checked, ~94 MB total):
//   [xb qb kb vb] (4x12.8MB) reused as hb (51.2MB) for FFN phase.
//   ob (12.8MB) reused as x1b: WoLN block reads its own 32 rows of ob into
//   accumulators before writing the same 32 rows as x1b — no cross-block overlap.
// ---------------------------------------------------------------------------

typedef short bf16x8 __attribute__((ext_vector_type(8)));
typedef float f32x4 __attribute__((ext_vector_type(4)));

__device__ inline unsigned short f2bf(float f) {
    unsigned int u = __float_as_uint(f);
    u += 0x7fffu + ((u >> 16) & 1u);   // round-to-nearest-even
    return (unsigned short)(u >> 16);
}
__device__ inline float bflo(unsigned int w) { return __uint_as_float(w << 16); }
__device__ inline float bfhi(unsigned int w) { return __uint_as_float(w & 0xffff0000u); }

// ------------------------------- CSR build ---------------------------------

__global__ void k_zero(int* __restrict__ p, int n) {
    int i = blockIdx.x * 256 + threadIdx.x;
    if (i < n) p[i] = 0;
}

__global__ void k_count(const int* __restrict__ ei, int* __restrict__ counts,
                        int E, int N) {
    int e = blockIdx.x * 256 + threadIdx.x;
    if (e >= E + N) return;
    int col = (e < E) ? ei[E + e] : (e - E);
    atomicAdd(&counts[col], 1);
}

__global__ void k_scan1(const int* __restrict__ counts, int* __restrict__ incl,
                        int* __restrict__ bsums, int N) {
    __shared__ int s[256];
    int t = threadIdx.x, i = blockIdx.x * 256 + t;
    int v = (i < N) ? counts[i] : 0;
    s[t] = v; __syncthreads();
    for (int off = 1; off < 256; off <<= 1) {
        int add = (t >= off) ? s[t - off] : 0;
        __syncthreads();
        s[t] += add;
        __syncthreads();
    }
    if (i < N) incl[i] = s[t];
    if (t == 255) bsums[blockIdx.x] = s[255];
}

__global__ void k_scan2(const int* __restrict__ bsums, int* __restrict__ boffs, int NB) {
    __shared__ int s[256];
    int t = threadIdx.x;
    int v = (t < NB) ? bsums[t] : 0;
    s[t] = v; __syncthreads();
    for (int off = 1; off < 256; off <<= 1) {
        int add = (t >= off) ? s[t - off] : 0;
        __syncthreads();
        s[t] += add;
        __syncthreads();
    }
    if (t < NB) boffs[t] = s[t] - v;   // exclusive
}

__global__ void k_scan3(const int* __restrict__ incl, const int* __restrict__ counts,
                        const int* __restrict__ boffs, int* __restrict__ nstart,
                        int* __restrict__ cursor, int N) {
    int i = blockIdx.x * 256 + threadIdx.x;
    if (i >= N) return;
    int st = incl[i] - counts[i] + boffs[blockIdx.x];
    nstart[i] = st;
    cursor[i] = st;
}

__global__ void k_fill(const int* __restrict__ ei, int* __restrict__ cursor,
                       int* __restrict__ csr, int E, int N) {
    int e = blockIdx.x * 256 + threadIdx.x;
    if (e >= E + N) return;
    int row, col;
    if (e < E) { row = ei[e]; col = ei[E + e]; }
    else       { row = col = e - E; }
    int pos = atomicAdd(&cursor[col], 1);
    csr[pos] = row;
}

// ------------------------------ prep (casts) -------------------------------

__global__ void k_cast(const float* __restrict__ x, unsigned short* __restrict__ xb,
                       int total4) {
    int i = blockIdx.x * 256 + threadIdx.x;
    if (i >= total4) return;
    float4 v = ((const float4*)x)[i];
    ushort4 o;
    o.x = f2bf(v.x); o.y = f2bf(v.y); o.z = f2bf(v.z); o.w = f2bf(v.w);
    ((ushort4*)xb)[i] = o;
}

// transpose fp32 [K][Co] -> bf16 [Co][K]
__global__ void k_prep(const float* Wq, const float* Wk, const float* Wv, const float* Wo,
                       const float* Wf1, const float* Wf2,
                       unsigned short* Wqt, unsigned short* Wkt, unsigned short* Wvt,
                       unsigned short* Wot, unsigned short* Wf1t, unsigned short* Wf2t) {
    int z = blockIdx.y;
    const float* in; unsigned short* out; int K, Co;
    switch (z) {
        case 0: in = Wq;  out = Wqt;  K = 128; Co = 128; break;
        case 1: in = Wk;  out = Wkt;  K = 128; Co = 128; break;
        case 2: in = Wv;  out = Wvt;  K = 128; Co = 128; break;
        case 3: in = Wo;  out = Wot;  K = 128; Co = 128; break;
        case 4: in = Wf1; out = Wf1t; K = 128; Co = 512; break;
        default: in = Wf2; out = Wf2t; K = 512; Co = 128; break;
    }
    int idx = blockIdx.x * 256 + threadIdx.x;
    if (idx >= K * Co) return;
    int k = idx / Co, c = idx % Co;
    out[c * K + k] = f2bf(in[idx]);
}

// --------------------------------- GEMM ------------------------------------
// Per-wave 32x32 output (2x2 tiles of 16x16). A: bf16 row-major [M2][K];
// Bt: bf16 [Cout][K]. Verified gfx950 layouts: A[m=lane&15][k=quad*8+j];
// B^T frags load identically; C/D: col=lane&15, row=quad*4+reg.
// EPI 0: store bf16.  EPI 2: +bias, gelu(erf), store bf16.

template <int EPI>
__global__ __launch_bounds__(256) void k_gemm(
    const unsigned short* __restrict__ A, const unsigned short* __restrict__ Bt,
    void* __restrict__ outp, const float* __restrict__ bias,
    int M, int K, int Cout) {
    int tid = threadIdx.x;
    int wid = tid >> 6, lane = tid & 63;
    int quad = lane >> 4, l16 = lane & 15;
    int m0 = blockIdx.x * 32;
    int n0 = blockIdx.y * 128 + wid * 32;

    const bf16x8* A0 = (const bf16x8*)(A + (size_t)(m0 + l16) * K);
    const bf16x8* A1 = (const bf16x8*)(A + (size_t)(m0 + 16 + l16) * K);
    const bf16x8* B0 = (const bf16x8*)(Bt + (size_t)(n0 + l16) * K);
    const bf16x8* B1 = (const bf16x8*)(Bt + (size_t)(n0 + 16 + l16) * K);

    f32x4 acc00 = {0.f, 0.f, 0.f, 0.f}, acc01 = acc00, acc10 = acc00, acc11 = acc00;
    int K8 = K >> 3;
    for (int k8 = 0; k8 < K8; k8 += 4) {
        bf16x8 a0 = A0[k8 + quad];
        bf16x8 a1 = A1[k8 + quad];
        bf16x8 b0 = B0[k8 + quad];
        bf16x8 b1 = B1[k8 + quad];
        acc00 = __builtin_amdgcn_mfma_f32_16x16x32_bf16(a0, b0, acc00, 0, 0, 0);
        acc01 = __builtin_amdgcn_mfma_f32_16x16x32_bf16(a0, b1, acc01, 0, 0, 0);
        acc10 = __builtin_amdgcn_mfma_f32_16x16x32_bf16(a1, b0, acc10, 0, 0, 0);
        acc11 = __builtin_amdgcn_mfma_f32_16x16x32_bf16(a1, b1, acc11, 0, 0, 0);
    }

    auto epi = [&](f32x4 a, int im, int in) {
        int col = n0 + in * 16 + l16;
#pragma unroll
        for (int r = 0; r < 4; ++r) {
            int row = m0 + im * 16 + quad * 4 + r;
            if (row >= M) continue;
            float v = a[r];
            if constexpr (EPI == 0) {
                ((unsigned short*)outp)[(size_t)row * Cout + col] = f2bf(v);
            } else {
                float g = v + bias[col];
                float y = 0.5f * g * (1.f + erff(g * 0.70710678118f));
                ((unsigned short*)outp)[(size_t)row * Cout + col] = f2bf(y);
            }
        }
    };
    epi(acc00, 0, 0); epi(acc01, 0, 1); epi(acc10, 1, 0); epi(acc11, 1, 1);
}

// --------------------- GEMM + bias + residual + LN (fused) -----------------
// One block = 32 rows x all 128 cols (4 waves, 32 cols each). Cout == 128.
// Phase 1: MFMA accumulate. Phase 2: acc+bias+resid -> LDS tile [32][130].
// Phase 3: 8 threads/row reduce mean/var (shfl_xor 1,2,4), write LN output.

__global__ __launch_bounds__(256) void k_gemm_ln(
    const unsigned short* __restrict__ A, const unsigned short* __restrict__ Bt,
    const float* __restrict__ bias, const float* __restrict__ resid,
    const float* __restrict__ g, const float* __restrict__ b,
    float* __restrict__ outf, unsigned short* __restrict__ outb,
    int M, int K) {
    __shared__ float s[32][130];
    int tid = threadIdx.x;
    int wid = tid >> 6, lane = tid & 63;
    int quad = lane >> 4, l16 = lane & 15;
    int m0 = blockIdx.x * 32;
    int n0 = wid * 32;

    const bf16x8* A0 = (const bf16x8*)(A + (size_t)(m0 + l16) * K);
    const bf16x8* A1 = (const bf16x8*)(A + (size_t)(m0 + 16 + l16) * K);
    const bf16x8* B0 = (const bf16x8*)(Bt + (size_t)(n0 + l16) * K);
    const bf16x8* B1 = (const bf16x8*)(Bt + (size_t)(n0 + 16 + l16) * K);

    f32x4 acc00 = {0.f, 0.f, 0.f, 0.f}, acc01 = acc00, acc10 = acc00, acc11 = acc00;
    int K8 = K >> 3;
    for (int k8 = 0; k8 < K8; k8 += 4) {
        bf16x8 a0 = A0[k8 + quad];
        bf16x8 a1 = A1[k8 + quad];
        bf16x8 b0 = B0[k8 + quad];
        bf16x8 b1 = B1[k8 + quad];
        acc00 = __builtin_amdgcn_mfma_f32_16x16x32_bf16(a0, b0, acc00, 0, 0, 0);
        acc01 = __builtin_amdgcn_mfma_f32_16x16x32_bf16(a0, b1, acc01, 0, 0, 0);
        acc10 = __builtin_amdgcn_mfma_f32_16x16x32_bf16(a1, b0, acc10, 0, 0, 0);
        acc11 = __builtin_amdgcn_mfma_f32_16x16x32_bf16(a1, b1, acc11, 0, 0, 0);
    }

    auto epi = [&](f32x4 a, int im, int in) {
        int col = n0 + in * 16 + l16;
#pragma unroll
        for (int r = 0; r < 4; ++r) {
            int row = im * 16 + quad * 4 + r;       // local row 0..31
            int grow = m0 + row;
            float rv = (grow < M) ? resid[(size_t)grow * 128 + col] : 0.f;
            s[row][col] = a[r] + bias[col] + rv;
        }
    };
    epi(acc00, 0, 0); epi(acc01, 0, 1); epi(acc10, 1, 0); epi(acc11, 1, 1);
    __syncthreads();

    int r = tid >> 3, c0 = (tid & 7) * 16;
    float sum = 0.f, sq = 0.f;
#pragma unroll
    for (int c = 0; c < 16; ++c) {
        float v = s[r][c0 + c];
        sum += v; sq += v * v;
    }
    sum += __shfl_xor(sum, 1); sq += __shfl_xor(sq, 1);
    sum += __shfl_xor(sum, 2); sq += __shfl_xor(sq, 2);
    sum += __shfl_xor(sum, 4); sq += __shfl_xor(sq, 4);
    float mean = sum * 0.0078125f;
    float var = sq * 0.0078125f - mean * mean;
    float rs = rsqrtf(var + 1e-5f);
    int grow = m0 + r;
    if (grow < M) {
#pragma unroll
        for (int c = 0; c < 16; ++c) {
            int col = c0 + c;
            float y = (s[r][col] - mean) * rs * g[col] + b[col];
            if (outf) outf[(size_t)grow * 128 + col] = y;
            if (outb) outb[(size_t)grow * 128 + col] = f2bf(y);
        }
    }
}

// ------------------------------ attention ----------------------------------
// One wave per destination node j. Lane l owns channels (2l, 2l+1); channel c
// belongs to head c/16, so lanes [8h,8h+8) hold head h -> 3 shfl_xor reduce
// the per-head dot. Online softmax in registers; one packed write per node.

__global__ __launch_bounds__(256) void k_attn(
    const unsigned short* __restrict__ qb, const unsigned short* __restrict__ kb,
    const unsigned short* __restrict__ vb, const int* __restrict__ nstart,
    const int* __restrict__ counts, const int* __restrict__ csr,
    unsigned short* __restrict__ ob, int N) {
    int j = blockIdx.x * 4 + (threadIdx.x >> 6);
    if (j >= N) return;
    int l = threadIdx.x & 63;

    const unsigned int* q2 = (const unsigned int*)qb;
    const unsigned int* k2 = (const unsigned int*)kb;
    const unsigned int* v2 = (const unsigned int*)vb;

    unsigned int kw = k2[(size_t)j * 64 + l];
    float kx = bflo(kw), ky = bfhi(kw);

    int start = nstart[j], cnt = counts[j];
    float m = -3.0e38f, lsum = 0.f, a0 = 0.f, a1 = 0.f;
    for (int i = 0; i < cnt; ++i) {
        int r = csr[start + i];
        unsigned int qw = q2[(size_t)r * 64 + l];
        float p = bflo(qw) * kx + bfhi(qw) * ky;
        p += __shfl_xor(p, 1);
        p += __shfl_xor(p, 2);
        p += __shfl_xor(p, 4);
        float sc = p * 0.25f;                 // 1/sqrt(16)
        float mnew = fmaxf(m, sc);
        float scale = __expf(m - mnew);
        float e = __expf(sc - mnew);
        lsum = lsum * scale + e;
        unsigned int vw = v2[(size_t)r * 64 + l];
        a0 = a0 * scale + e * bflo(vw);
        a1 = a1 * scale + e * bfhi(vw);
        m = mnew;
    }
    float inv = 1.f / (lsum + 1e-8f);
    unsigned int w = ((unsigned int)f2bf(a1 * inv) << 16) | (unsigned int)f2bf(a0 * inv);
    ((unsigned int*)ob)[(size_t)j * 64 + l] = w;
}

// -------------------------------- launch -----------------------------------

extern "C" void kernel_launch(void* const* d_in, const int* in_sizes, int n_in,
                              void* d_out, int out_size, void* d_ws, size_t ws_size,
                              hipStream_t stream) {
    const float* x   = (const float*)d_in[0];
    const int* ei    = (const int*)d_in[1];      // harness materializes int64 as int32
    const float* Wq  = (const float*)d_in[2];
    const float* Wk  = (const float*)d_in[3];
    const float* Wv  = (const float*)d_in[4];
    const float* Wo  = (const float*)d_in[5];
    const float* bo  = (const float*)d_in[6];
    const float* Wf1 = (const float*)d_in[7];
    const float* bf1 = (const float*)d_in[8];
    const float* Wf2 = (const float*)d_in[9];
    const float* bf2 = (const float*)d_in[10];
    const float* g1  = (const float*)d_in[11];
    const float* b1  = (const float*)d_in[12];
    const float* g2  = (const float*)d_in[13];
    const float* b2  = (const float*)d_in[14];

    int N = in_sizes[0] / 128;
    int E = in_sizes[1] / 2;
    int N2 = ((N + 31) / 32) * 32;     // GEMM row padding
    int NE = E + N;
    size_t NR = (size_t)N2 * 128;      // elements per bf16 [N2][128] buffer

    char* p = (char*)d_ws;
    auto alloc = [&](size_t bytes) -> char* {
        char* r = p;
        p += (bytes + 255) & ~(size_t)255;
        return r;
    };
    // Region R0: xb|qb|kb|vb, reused later as hb (FFN hidden, [N2][512] bf16).
    unsigned short* xb = (unsigned short*)alloc(NR * 2 * 4);
    unsigned short* qb = xb + NR;
    unsigned short* kb = qb + NR;
    unsigned short* vb = kb + NR;
    unsigned short* hb = xb;                      // alias (lifetime disjoint)
    // ob reused as x1b (block-local read-then-write, no cross-block overlap).
    unsigned short* ob  = (unsigned short*)alloc(NR * 2);
    unsigned short* x1b = ob;                     // alias
    float* x1f          = (float*)alloc((size_t)N * 128 * 4);
    unsigned short* Wqt  = (unsigned short*)alloc(128 * 128 * 2);
    unsigned short* Wkt  = (unsigned short*)alloc(128 * 128 * 2);
    unsigned short* Wvt  = (unsigned short*)alloc(128 * 128 * 2);
    unsigned short* Wot  = (unsigned short*)alloc(128 * 128 * 2);
    unsigned short* Wf1t = (unsigned short*)alloc(512 * 128 * 2);
    unsigned short* Wf2t = (unsigned short*)alloc(128 * 512 * 2);
    int* counts = (int*)alloc((size_t)N * 4);
    int* incl   = (int*)alloc((size_t)N * 4);
    int* nstart = (int*)alloc((size_t)N * 4);
    int* cursor = (int*)alloc((size_t)N * 4);
    int* bsums  = (int*)alloc(1024 * 4);
    int* boffs  = (int*)alloc(1024 * 4);
    int* csr    = (int*)alloc((size_t)NE * 4);

    int NB = (N + 255) / 256;          // 196 (<256, fits one-block scan2)
    int M2 = (N + 31) / 32;

    k_zero<<<NB, 256, 0, stream>>>(counts, N);
    k_count<<<(NE + 255) / 256, 256, 0, stream>>>(ei, counts, E, N);
    k_scan1<<<NB, 256, 0, stream>>>(counts, incl, bsums, N);
    k_scan2<<<1, 256, 0, stream>>>(bsums, boffs, NB);
    k_scan3<<<NB, 256, 0, stream>>>(incl, counts, boffs, nstart, cursor, N);
    k_fill<<<(NE + 255) / 256, 256, 0, stream>>>(ei, cursor, csr, E, N);

    k_cast<<<((N * 128 / 4) + 255) / 256, 256, 0, stream>>>(x, xb, N * 128 / 4);
    k_prep<<<dim3(256, 6), 256, 0, stream>>>(Wq, Wk, Wv, Wo, Wf1, Wf2,
                                             Wqt, Wkt, Wvt, Wot, Wf1t, Wf2t);

    k_gemm<0><<<dim3(M2, 1), 256, 0, stream>>>(xb, Wqt, qb, nullptr, N, 128, 128);
    k_gemm<0><<<dim3(M2, 1), 256, 0, stream>>>(xb, Wkt, kb, nullptr, N, 128, 128);
    k_gemm<0><<<dim3(M2, 1), 256, 0, stream>>>(xb, Wvt, vb, nullptr, N, 128, 128);

    k_attn<<<(N + 3) / 4, 256, 0, stream>>>(qb, kb, vb, nstart, counts, csr, ob, N);

    // Wo + bias + residual(x) + LN1 -> x1f (fp32), x1b (bf16, aliases ob)
    k_gemm_ln<<<dim3(M2), 256, 0, stream>>>(ob, Wot, bo, x, g1, b1, x1f, x1b, N, 128);

    // FFN1 + gelu -> hb (bf16, aliases xb..vb)
    k_gemm<2><<<dim3(M2, 4), 256, 0, stream>>>(x1b, Wf1t, hb, bf1, N, 128, 512);

    // FFN2 + bias + residual(x1f) + LN2 -> d_out (fp32)
    k_gemm_ln<<<dim3(M2), 256, 0, stream>>>(hb, Wf2t, bf2, x1f, g2, b2,
                                            (float*)d_out, nullptr, N, 512);
}

// Round 3
// 518.317 us; speedup vs baseline: 1.1279x; 1.1279x over previous
//
#include <hip/hip_runtime.h>
#include <cmath>

// ---------------------------------------------------------------------------
// GraphTransformerLayer on MI355X (gfx950).
// N=50000 nodes, C=128, H=8 heads, D=16, E=800000 edges (+N self loops).
//
// Pipeline (12 dispatches):
//   zero -> CSR build (count/scan x3/fill)     [edge_index arrives as INT32]
//   k_prep: weights -> bf16 [Cout][K] (Wq|Wk|Wv contiguous)
//   k_gemm_qkv: fused QKV, fp32 A cvt in-reg   -> qkv bf16 [N][384]
//   k_attn: 1 wave/dest node, 4-edge batches   -> ob bf16
//   Wo GEMM + bias + residual + LN1 (fused)    -> x1f fp32, x1b bf16
//   FFN1 GEMM + gelu                           -> hb bf16
//   FFN2 GEMM + bias + residual + LN2 (fused)  -> d_out fp32
//
// Workspace aliasing (lifetime-checked, ~94 MB):
//   R0 = [qkv 38.4MB | ob 12.8MB] reused as hb (51.2MB) after Wo-GEMM.
//   Padded rows >= N are poison but only feed output rows >= N (guarded).
// ---------------------------------------------------------------------------

typedef short bf16x8 __attribute__((ext_vector_type(8)));
typedef float f32x4 __attribute__((ext_vector_type(4)));

__device__ inline unsigned short f2bf(float f) {
    unsigned int u = __float_as_uint(f);
    u += 0x7fffu + ((u >> 16) & 1u);   // round-to-nearest-even
    return (unsigned short)(u >> 16);
}
__device__ inline float bflo(unsigned int w) { return __uint_as_float(w << 16); }
__device__ inline float bfhi(unsigned int w) { return __uint_as_float(w & 0xffff0000u); }

// ------------------------------- CSR build ---------------------------------

__global__ void k_zero(int* __restrict__ p, int n) {
    int i = blockIdx.x * 256 + threadIdx.x;
    if (i < n) p[i] = 0;
}

__global__ void k_count(const int* __restrict__ ei, int* __restrict__ counts,
                        int E, int N) {
    int e = blockIdx.x * 256 + threadIdx.x;
    if (e >= E + N) return;
    int col = (e < E) ? ei[E + e] : (e - E);
    atomicAdd(&counts[col], 1);
}

__global__ void k_scan1(const int* __restrict__ counts, int* __restrict__ incl,
                        int* __restrict__ bsums, int N) {
    __shared__ int s[256];
    int t = threadIdx.x, i = blockIdx.x * 256 + t;
    int v = (i < N) ? counts[i] : 0;
    s[t] = v; __syncthreads();
    for (int off = 1; off < 256; off <<= 1) {
        int add = (t >= off) ? s[t - off] : 0;
        __syncthreads();
        s[t] += add;
        __syncthreads();
    }
    if (i < N) incl[i] = s[t];
    if (t == 255) bsums[blockIdx.x] = s[255];
}

__global__ void k_scan2(const int* __restrict__ bsums, int* __restrict__ boffs, int NB) {
    __shared__ int s[256];
    int t = threadIdx.x;
    int v = (t < NB) ? bsums[t] : 0;
    s[t] = v; __syncthreads();
    for (int off = 1; off < 256; off <<= 1) {
        int add = (t >= off) ? s[t - off] : 0;
        __syncthreads();
        s[t] += add;
        __syncthreads();
    }
    if (t < NB) boffs[t] = s[t] - v;   // exclusive
}

__global__ void k_scan3(const int* __restrict__ incl, const int* __restrict__ counts,
                        const int* __restrict__ boffs, int* __restrict__ nstart,
                        int* __restrict__ cursor, int N) {
    int i = blockIdx.x * 256 + threadIdx.x;
    if (i >= N) return;
    int st = incl[i] - counts[i] + boffs[blockIdx.x];
    nstart[i] = st;
    cursor[i] = st;
}

__global__ void k_fill(const int* __restrict__ ei, int* __restrict__ cursor,
                       int* __restrict__ csr, int E, int N) {
    int e = blockIdx.x * 256 + threadIdx.x;
    if (e >= E + N) return;
    int row, col;
    if (e < E) { row = ei[e]; col = ei[E + e]; }
    else       { row = col = e - E; }
    int pos = atomicAdd(&cursor[col], 1);
    csr[pos] = row;
}

// ------------------------------ weight prep --------------------------------
// transpose fp32 [K][Co] -> bf16 [Co][K].  Wq/Wk/Wv land contiguously.

__global__ void k_prep(const float* Wq, const float* Wk, const float* Wv, const float* Wo,
                       const float* Wf1, const float* Wf2,
                       unsigned short* Wqkvt, unsigned short* Wot,
                       unsigned short* Wf1t, unsigned short* Wf2t) {
    int z = blockIdx.y;
    const float* in; unsigned short* out; int K, Co;
    switch (z) {
        case 0: in = Wq;  out = Wqkvt;          K = 128; Co = 128; break;
        case 1: in = Wk;  out = Wqkvt + 16384;  K = 128; Co = 128; break;
        case 2: in = Wv;  out = Wqkvt + 32768;  K = 128; Co = 128; break;
        case 3: in = Wo;  out = Wot;            K = 128; Co = 128; break;
        case 4: in = Wf1; out = Wf1t;           K = 128; Co = 512; break;
        default: in = Wf2; out = Wf2t;          K = 512; Co = 128; break;
    }
    int idx = blockIdx.x * 256 + threadIdx.x;
    if (idx >= K * Co) return;
    int k = idx / Co, c = idx % Co;
    out[c * K + k] = f2bf(in[idx]);
}

// ------------------------------ fused QKV GEMM -----------------------------
// Block = 32 rows; wave wid covers cols [wid*32, wid*32+32) of EACH slab.
// A read once (fp32, cvt in-register), 3 accumulator sets -> qkv [N][384].

__global__ __launch_bounds__(256) void k_gemm_qkv(
    const float* __restrict__ x, const unsigned short* __restrict__ Wt3,
    unsigned short* __restrict__ qkv, int M) {
    int tid = threadIdx.x;
    int wid = tid >> 6, lane = tid & 63;
    int quad = lane >> 4, l16 = lane & 15;
    int m0 = blockIdx.x * 32;
    int n0 = wid * 32;

    int ra0 = min(m0 + l16, M - 1);
    int ra1 = min(m0 + 16 + l16, M - 1);
    const float4* A0 = (const float4*)(x + (size_t)ra0 * 128);
    const float4* A1 = (const float4*)(x + (size_t)ra1 * 128);
    const bf16x8* B0[3]; const bf16x8* B1[3];
#pragma unroll
    for (int s = 0; s < 3; ++s) {
        B0[s] = (const bf16x8*)(Wt3 + s * 16384 + (size_t)(n0 + l16) * 128);
        B1[s] = (const bf16x8*)(Wt3 + s * 16384 + (size_t)(n0 + 16 + l16) * 128);
    }

    f32x4 acc[3][4];
#pragma unroll
    for (int s = 0; s < 3; ++s)
#pragma unroll
        for (int t = 0; t < 4; ++t) acc[s][t] = {0.f, 0.f, 0.f, 0.f};

    auto cvt8 = [](float4 u, float4 v) {
        bf16x8 r;
        r[0] = (short)f2bf(u.x); r[1] = (short)f2bf(u.y);
        r[2] = (short)f2bf(u.z); r[3] = (short)f2bf(u.w);
        r[4] = (short)f2bf(v.x); r[5] = (short)f2bf(v.y);
        r[6] = (short)f2bf(v.z); r[7] = (short)f2bf(v.w);
        return r;
    };

#pragma unroll
    for (int k8 = 0; k8 < 16; k8 += 4) {
        int kb = k8 + quad;
        bf16x8 a0 = cvt8(A0[kb * 2], A0[kb * 2 + 1]);
        bf16x8 a1 = cvt8(A1[kb * 2], A1[kb * 2 + 1]);
#pragma unroll
        for (int s = 0; s < 3; ++s) {
            bf16x8 b0 = B0[s][kb];
            bf16x8 b1 = B1[s][kb];
            acc[s][0] = __builtin_amdgcn_mfma_f32_16x16x32_bf16(a0, b0, acc[s][0], 0, 0, 0);
            acc[s][1] = __builtin_amdgcn_mfma_f32_16x16x32_bf16(a0, b1, acc[s][1], 0, 0, 0);
            acc[s][2] = __builtin_amdgcn_mfma_f32_16x16x32_bf16(a1, b0, acc[s][2], 0, 0, 0);
            acc[s][3] = __builtin_amdgcn_mfma_f32_16x16x32_bf16(a1, b1, acc[s][3], 0, 0, 0);
        }
    }

#pragma unroll
    for (int s = 0; s < 3; ++s) {
#pragma unroll
        for (int t = 0; t < 4; ++t) {
            int im = t >> 1, in = t & 1;
            int col = n0 + in * 16 + l16;
#pragma unroll
            for (int r = 0; r < 4; ++r) {
                int row = m0 + im * 16 + quad * 4 + r;
                if (row < M)
                    qkv[(size_t)row * 384 + s * 128 + col] = f2bf(acc[s][t][r]);
            }
        }
    }
}

// --------------------------------- GEMM ------------------------------------
// Per-wave 32x32 out; A bf16 row-major [M2][K]; Bt bf16 [Cout][K].
// EPI 2: +bias, gelu(erf), store bf16.

template <int EPI>
__global__ __launch_bounds__(256) void k_gemm(
    const unsigned short* __restrict__ A, const unsigned short* __restrict__ Bt,
    void* __restrict__ outp, const float* __restrict__ bias,
    int M, int K, int Cout) {
    int tid = threadIdx.x;
    int wid = tid >> 6, lane = tid & 63;
    int quad = lane >> 4, l16 = lane & 15;
    int m0 = blockIdx.x * 32;
    int n0 = blockIdx.y * 128 + wid * 32;

    const bf16x8* A0 = (const bf16x8*)(A + (size_t)(m0 + l16) * K);
    const bf16x8* A1 = (const bf16x8*)(A + (size_t)(m0 + 16 + l16) * K);
    const bf16x8* B0 = (const bf16x8*)(Bt + (size_t)(n0 + l16) * K);
    const bf16x8* B1 = (const bf16x8*)(Bt + (size_t)(n0 + 16 + l16) * K);

    f32x4 acc00 = {0.f, 0.f, 0.f, 0.f}, acc01 = acc00, acc10 = acc00, acc11 = acc00;
    int K8 = K >> 3;
    for (int k8 = 0; k8 < K8; k8 += 4) {
        bf16x8 a0 = A0[k8 + quad];
        bf16x8 a1 = A1[k8 + quad];
        bf16x8 b0 = B0[k8 + quad];
        bf16x8 b1 = B1[k8 + quad];
        acc00 = __builtin_amdgcn_mfma_f32_16x16x32_bf16(a0, b0, acc00, 0, 0, 0);
        acc01 = __builtin_amdgcn_mfma_f32_16x16x32_bf16(a0, b1, acc01, 0, 0, 0);
        acc10 = __builtin_amdgcn_mfma_f32_16x16x32_bf16(a1, b0, acc10, 0, 0, 0);
        acc11 = __builtin_amdgcn_mfma_f32_16x16x32_bf16(a1, b1, acc11, 0, 0, 0);
    }

    auto epi = [&](f32x4 a, int im, int in) {
        int col = n0 + in * 16 + l16;
#pragma unroll
        for (int r = 0; r < 4; ++r) {
            int row = m0 + im * 16 + quad * 4 + r;
            if (row >= M) continue;
            float g = a[r] + bias[col];
            float y = 0.5f * g * (1.f + erff(g * 0.70710678118f));
            ((unsigned short*)outp)[(size_t)row * Cout + col] = f2bf(y);
        }
    };
    epi(acc00, 0, 0); epi(acc01, 0, 1); epi(acc10, 1, 0); epi(acc11, 1, 1);
}

// --------------------- GEMM + bias + residual + LN (fused) -----------------

__global__ __launch_bounds__(256) void k_gemm_ln(
    const unsigned short* __restrict__ A, const unsigned short* __restrict__ Bt,
    const float* __restrict__ bias, const float* __restrict__ resid,
    const float* __restrict__ g, const float* __restrict__ b,
    float* __restrict__ outf, unsigned short* __restrict__ outb,
    int M, int K) {
    __shared__ float s[32][130];
    int tid = threadIdx.x;
    int wid = tid >> 6, lane = tid & 63;
    int quad = lane >> 4, l16 = lane & 15;
    int m0 = blockIdx.x * 32;
    int n0 = wid * 32;

    const bf16x8* A0 = (const bf16x8*)(A + (size_t)(m0 + l16) * K);
    const bf16x8* A1 = (const bf16x8*)(A + (size_t)(m0 + 16 + l16) * K);
    const bf16x8* B0 = (const bf16x8*)(Bt + (size_t)(n0 + l16) * K);
    const bf16x8* B1 = (const bf16x8*)(Bt + (size_t)(n0 + 16 + l16) * K);

    f32x4 acc00 = {0.f, 0.f, 0.f, 0.f}, acc01 = acc00, acc10 = acc00, acc11 = acc00;
    int K8 = K >> 3;
    for (int k8 = 0; k8 < K8; k8 += 4) {
        bf16x8 a0 = A0[k8 + quad];
        bf16x8 a1 = A1[k8 + quad];
        bf16x8 b0 = B0[k8 + quad];
        bf16x8 b1 = B1[k8 + quad];
        acc00 = __builtin_amdgcn_mfma_f32_16x16x32_bf16(a0, b0, acc00, 0, 0, 0);
        acc01 = __builtin_amdgcn_mfma_f32_16x16x32_bf16(a0, b1, acc01, 0, 0, 0);
        acc10 = __builtin_amdgcn_mfma_f32_16x16x32_bf16(a1, b0, acc10, 0, 0, 0);
        acc11 = __builtin_amdgcn_mfma_f32_16x16x32_bf16(a1, b1, acc11, 0, 0, 0);
    }

    auto epi = [&](f32x4 a, int im, int in) {
        int col = n0 + in * 16 + l16;
#pragma unroll
        for (int r = 0; r < 4; ++r) {
            int row = im * 16 + quad * 4 + r;       // local row 0..31
            int grow = m0 + row;
            float rv = (grow < M) ? resid[(size_t)grow * 128 + col] : 0.f;
            s[row][col] = a[r] + bias[col] + rv;
        }
    };
    epi(acc00, 0, 0); epi(acc01, 0, 1); epi(acc10, 1, 0); epi(acc11, 1, 1);
    __syncthreads();

    int r = tid >> 3, c0 = (tid & 7) * 16;
    float sum = 0.f, sq = 0.f;
#pragma unroll
    for (int c = 0; c < 16; ++c) {
        float v = s[r][c0 + c];
        sum += v; sq += v * v;
    }
    sum += __shfl_xor(sum, 1); sq += __shfl_xor(sq, 1);
    sum += __shfl_xor(sum, 2); sq += __shfl_xor(sq, 2);
    sum += __shfl_xor(sum, 4); sq += __shfl_xor(sq, 4);
    float mean = sum * 0.0078125f;
    float var = sq * 0.0078125f - mean * mean;
    float rs = rsqrtf(var + 1e-5f);
    int grow = m0 + r;
    if (grow < M) {
#pragma unroll
        for (int c = 0; c < 16; ++c) {
            int col = c0 + c;
            float y = (s[r][col] - mean) * rs * g[col] + b[col];
            if (outf) outf[(size_t)grow * 128 + col] = y;
            if (outb) outb[(size_t)grow * 128 + col] = f2bf(y);
        }
    }
}

// ------------------------------ attention ----------------------------------
// One wave per destination node j; qkv row = [q|k|v] (192 dwords). Lane l
// owns channels (2l,2l+1); lanes 8h..8h+7 hold head h -> 3 shfl_xor reduce.
// 4-edge batches: 8 gathers in flight, one batched online-softmax update.

__global__ __launch_bounds__(256) void k_attn(
    const unsigned int* __restrict__ qkv, const int* __restrict__ nstart,
    const int* __restrict__ counts, const int* __restrict__ csr,
    unsigned int* __restrict__ ob, int N) {
    int j = blockIdx.x * 4 + (threadIdx.x >> 6);
    if (j >= N) return;
    int l = threadIdx.x & 63;

    unsigned int kw = qkv[(size_t)j * 192 + 64 + l];
    float kx = bflo(kw), ky = bfhi(kw);

    int start = nstart[j], cnt = counts[j];
    float m = -3.0e38f, lsum = 0.f, a0 = 0.f, a1 = 0.f;
    int i = 0;
    for (; i + 4 <= cnt; i += 4) {
        int r0 = csr[start + i + 0], r1 = csr[start + i + 1];
        int r2 = csr[start + i + 2], r3 = csr[start + i + 3];
        unsigned int qw0 = qkv[(size_t)r0 * 192 + l];
        unsigned int qw1 = qkv[(size_t)r1 * 192 + l];
        unsigned int qw2 = qkv[(size_t)r2 * 192 + l];
        unsigned int qw3 = qkv[(size_t)r3 * 192 + l];
        unsigned int vw0 = qkv[(size_t)r0 * 192 + 128 + l];
        unsigned int vw1 = qkv[(size_t)r1 * 192 + 128 + l];
        unsigned int vw2 = qkv[(size_t)r2 * 192 + 128 + l];
        unsigned int vw3 = qkv[(size_t)r3 * 192 + 128 + l];

        float p0 = fmaf(bflo(qw0), kx, bfhi(qw0) * ky);
        float p1 = fmaf(bflo(qw1), kx, bfhi(qw1) * ky);
        float p2 = fmaf(bflo(qw2), kx, bfhi(qw2) * ky);
        float p3 = fmaf(bflo(qw3), kx, bfhi(qw3) * ky);
        p0 += __shfl_xor(p0, 1); p1 += __shfl_xor(p1, 1);
        p2 += __shfl_xor(p2, 1); p3 += __shfl_xor(p3, 1);
        p0 += __shfl_xor(p0, 2); p1 += __shfl_xor(p1, 2);
        p2 += __shfl_xor(p2, 2); p3 += __shfl_xor(p3, 2);
        p0 += __shfl_xor(p0, 4); p1 += __shfl_xor(p1, 4);
        p2 += __shfl_xor(p2, 4); p3 += __shfl_xor(p3, 4);
        float s0 = p0 * 0.25f, s1 = p1 * 0.25f, s2 = p2 * 0.25f, s3 = p3 * 0.25f;

        float mn = fmaxf(fmaxf(fmaxf(s0, s1), fmaxf(s2, s3)), m);
        float scale = __expf(m - mn);
        float e0 = __expf(s0 - mn), e1 = __expf(s1 - mn);
        float e2 = __expf(s2 - mn), e3 = __expf(s3 - mn);
        lsum = lsum * scale + ((e0 + e1) + (e2 + e3));
        a0 = a0 * scale + e0 * bflo(vw0) + e1 * bflo(vw1) + e2 * bflo(vw2) + e3 * bflo(vw3);
        a1 = a1 * scale + e0 * bfhi(vw0) + e1 * bfhi(vw1) + e2 * bfhi(vw2) + e3 * bfhi(vw3);
        m = mn;
    }
    for (; i < cnt; ++i) {
        int r = csr[start + i];
        unsigned int qw = qkv[(size_t)r * 192 + l];
        unsigned int vw = qkv[(size_t)r * 192 + 128 + l];
        float p = fmaf(bflo(qw), kx, bfhi(qw) * ky);
        p += __shfl_xor(p, 1);
        p += __shfl_xor(p, 2);
        p += __shfl_xor(p, 4);
        float sc = p * 0.25f;
        float mn = fmaxf(m, sc);
        float scale = __expf(m - mn);
        float e = __expf(sc - mn);
        lsum = lsum * scale + e;
        a0 = a0 * scale + e * bflo(vw);
        a1 = a1 * scale + e * bfhi(vw);
        m = mn;
    }
    float inv = 1.f / (lsum + 1e-8f);
    unsigned int w = ((unsigned int)f2bf(a1 * inv) << 16) | (unsigned int)f2bf(a0 * inv);
    ob[(size_t)j * 64 + l] = w;
}

// -------------------------------- launch -----------------------------------

extern "C" void kernel_launch(void* const* d_in, const int* in_sizes, int n_in,
                              void* d_out, int out_size, void* d_ws, size_t ws_size,
                              hipStream_t stream) {
    const float* x   = (const float*)d_in[0];
    const int* ei    = (const int*)d_in[1];      // int64 materialized as int32
    const float* Wq  = (const float*)d_in[2];
    const float* Wk  = (const float*)d_in[3];
    const float* Wv  = (const float*)d_in[4];
    const float* Wo  = (const float*)d_in[5];
    const float* bo  = (const float*)d_in[6];
    const float* Wf1 = (const float*)d_in[7];
    const float* bf1 = (const float*)d_in[8];
    const float* Wf2 = (const float*)d_in[9];
    const float* bf2 = (const float*)d_in[10];
    const float* g1  = (const float*)d_in[11];
    const float* b1  = (const float*)d_in[12];
    const float* g2  = (const float*)d_in[13];
    const float* b2  = (const float*)d_in[14];

    int N = in_sizes[0] / 128;
    int E = in_sizes[1] / 2;
    int N2 = ((N + 31) / 32) * 32;
    int NE = E + N;

    char* p = (char*)d_ws;
    auto alloc = [&](size_t bytes) -> char* {
        char* r = p;
        p += (bytes + 255) & ~(size_t)255;
        return r;
    };
    // R0: [qkv (N2*384) | ob (N2*128)] bf16, reused as hb (N2*512) for FFN.
    unsigned short* qkv = (unsigned short*)alloc((size_t)N2 * 512 * 2);
    unsigned short* ob  = qkv + (size_t)N2 * 384;
    unsigned short* hb  = qkv;                   // alias (lifetime disjoint)
    unsigned short* x1b = (unsigned short*)alloc((size_t)N2 * 128 * 2);
    float* x1f          = (float*)alloc((size_t)N * 128 * 4);
    unsigned short* Wqkvt = (unsigned short*)alloc(3 * 128 * 128 * 2);
    unsigned short* Wot   = (unsigned short*)alloc(128 * 128 * 2);
    unsigned short* Wf1t  = (unsigned short*)alloc(512 * 128 * 2);
    unsigned short* Wf2t  = (unsigned short*)alloc(128 * 512 * 2);
    int* counts = (int*)alloc((size_t)N * 4);
    int* incl   = (int*)alloc((size_t)N * 4);
    int* nstart = (int*)alloc((size_t)N * 4);
    int* cursor = (int*)alloc((size_t)N * 4);
    int* bsums  = (int*)alloc(1024 * 4);
    int* boffs  = (int*)alloc(1024 * 4);
    int* csr    = (int*)alloc((size_t)NE * 4);

    int NB = (N + 255) / 256;          // 196 (<256, one-block scan2)
    int M2 = (N + 31) / 32;

    k_zero<<<NB, 256, 0, stream>>>(counts, N);
    k_count<<<(NE + 255) / 256, 256, 0, stream>>>(ei, counts, E, N);
    k_scan1<<<NB, 256, 0, stream>>>(counts, incl, bsums, N);
    k_scan2<<<1, 256, 0, stream>>>(bsums, boffs, NB);
    k_scan3<<<NB, 256, 0, stream>>>(incl, counts, boffs, nstart, cursor, N);
    k_fill<<<(NE + 255) / 256, 256, 0, stream>>>(ei, cursor, csr, E, N);

    k_prep<<<dim3(256, 6), 256, 0, stream>>>(Wq, Wk, Wv, Wo, Wf1, Wf2,
                                             Wqkvt, Wot, Wf1t, Wf2t);

    k_gemm_qkv<<<dim3(M2), 256, 0, stream>>>(x, Wqkvt, qkv, N);

    k_attn<<<(N + 3) / 4, 256, 0, stream>>>((const unsigned int*)qkv, nstart,
                                            counts, csr, (unsigned int*)ob, N);

    // Wo + bias + residual(x) + LN1 -> x1f (fp32), x1b (bf16)
    k_gemm_ln<<<dim3(M2), 256, 0, stream>>>(ob, Wot, bo, x, g1, b1, x1f, x1b, N, 128);

    // FFN1 + gelu -> hb (aliases qkv|ob, both dead)
    k_gemm<2><<<dim3(M2, 4), 256, 0, stream>>>(x1b, Wf1t, hb, bf1, N, 128, 512);

    // FFN2 + bias + residual(x1f) + LN2 -> d_out (fp32)
    k_gemm_ln<<<dim3(M2), 256, 0, stream>>>(hb, Wf2t, bf2, x1f, g2, b2,
                                            (float*)d_out, nullptr, N, 512);
}

// Round 4
// 387.032 us; speedup vs baseline: 1.5104x; 1.3392x over previous
//
#include <hip/hip_runtime.h>
#include <cmath>

// ---------------------------------------------------------------------------
// GraphTransformerLayer on MI355X (gfx950).
// N=50000 nodes, C=128, H=8 heads, D=16, E=800000 edges (+N self loops).
//
// Pipeline (13 dispatches):
//   zero -> CSR build (count/scan x3/fill)      [edge_index arrives as INT32]
//   k_prep: weights -> bf16 [Cout][K] (Wq|Wk|Wv contiguous) ; k_cast x->bf16
//   k_gemm_big<0>: QKV (Cout=384, grid.y=3)     -> qkv bf16 [N][384]
//   k_attn: 1 wave/dest node, 4-edge batches    -> ob bf16
//   k_gemm_big<2>: Wo + bias + resid + LN1      -> x1f fp32, x1b bf16
//   k_gemm_big<1>: FFN1 + gelu                  -> hb bf16
//   k_gemm_big<2>: FFN2 + bias + resid + LN2    -> d_out fp32
//
// GEMM structure (m97 ladder): 128x128 block tile, BK=64, 4 waves as 2x2,
// 64x64 per wave (16 accs). A/B tiles staged to LDS via global_load_lds
// width=16 (contiguous 1KB/wave-instr); XOR swizzle (chunk ^ row&7) applied
// on the GLOBAL address side so ds_read_b128 fragments are ~conflict-free.
// LN fused: shuffle row-partials + 2KB LDS, no big LN tile.
//
// Workspace aliasing (lifetime-checked, ~94 MB):
//   R0 = [qkv 38.4MB | ob 12.8MB] reused as hb (51.2MB) after Wo-GEMM.
//   xb (bf16 x) aliases x1b: xb dead after QKV GEMM, x1b written by Wo-LN.
// ---------------------------------------------------------------------------

typedef short bf16x8 __attribute__((ext_vector_type(8)));
typedef float f32x4 __attribute__((ext_vector_type(4)));
typedef unsigned int uint_as1 __attribute__((address_space(1)));
typedef unsigned int uint_as3 __attribute__((address_space(3)));

__device__ inline unsigned short f2bf(float f) {
    unsigned int u = __float_as_uint(f);
    u += 0x7fffu + ((u >> 16) & 1u);   // round-to-nearest-even
    return (unsigned short)(u >> 16);
}
__device__ inline float bflo(unsigned int w) { return __uint_as_float(w << 16); }
__device__ inline float bfhi(unsigned int w) { return __uint_as_float(w & 0xffff0000u); }

__device__ inline void gload16(const unsigned short* g, unsigned short* l) {
    __builtin_amdgcn_global_load_lds((const uint_as1*)g, (uint_as3*)l, 16, 0, 0);
}

// ------------------------------- CSR build ---------------------------------

__global__ void k_zero(int* __restrict__ p, int n) {
    int i = blockIdx.x * 256 + threadIdx.x;
    if (i < n) p[i] = 0;
}

__global__ void k_count(const int* __restrict__ ei, int* __restrict__ counts,
                        int E, int N) {
    int e = blockIdx.x * 256 + threadIdx.x;
    if (e >= E + N) return;
    int col = (e < E) ? ei[E + e] : (e - E);
    atomicAdd(&counts[col], 1);
}

__global__ void k_scan1(const int* __restrict__ counts, int* __restrict__ incl,
                        int* __restrict__ bsums, int N) {
    __shared__ int s[256];
    int t = threadIdx.x, i = blockIdx.x * 256 + t;
    int v = (i < N) ? counts[i] : 0;
    s[t] = v; __syncthreads();
    for (int off = 1; off < 256; off <<= 1) {
        int add = (t >= off) ? s[t - off] : 0;
        __syncthreads();
        s[t] += add;
        __syncthreads();
    }
    if (i < N) incl[i] = s[t];
    if (t == 255) bsums[blockIdx.x] = s[255];
}

__global__ void k_scan2(const int* __restrict__ bsums, int* __restrict__ boffs, int NB) {
    __shared__ int s[256];
    int t = threadIdx.x;
    int v = (t < NB) ? bsums[t] : 0;
    s[t] = v; __syncthreads();
    for (int off = 1; off < 256; off <<= 1) {
        int add = (t >= off) ? s[t - off] : 0;
        __syncthreads();
        s[t] += add;
        __syncthreads();
    }
    if (t < NB) boffs[t] = s[t] - v;   // exclusive
}

__global__ void k_scan3(const int* __restrict__ incl, const int* __restrict__ counts,
                        const int* __restrict__ boffs, int* __restrict__ nstart,
                        int* __restrict__ cursor, int N) {
    int i = blockIdx.x * 256 + threadIdx.x;
    if (i >= N) return;
    int st = incl[i] - counts[i] + boffs[blockIdx.x];
    nstart[i] = st;
    cursor[i] = st;
}

__global__ void k_fill(const int* __restrict__ ei, int* __restrict__ cursor,
                       int* __restrict__ csr, int E, int N) {
    int e = blockIdx.x * 256 + threadIdx.x;
    if (e >= E + N) return;
    int row, col;
    if (e < E) { row = ei[e]; col = ei[E + e]; }
    else       { row = col = e - E; }
    int pos = atomicAdd(&cursor[col], 1);
    csr[pos] = row;
}

// ------------------------------ prep (casts) -------------------------------

__global__ void k_cast(const float* __restrict__ x, unsigned short* __restrict__ xb,
                       int total4) {
    int i = blockIdx.x * 256 + threadIdx.x;
    if (i >= total4) return;
    float4 v = ((const float4*)x)[i];
    ushort4 o;
    o.x = f2bf(v.x); o.y = f2bf(v.y); o.z = f2bf(v.z); o.w = f2bf(v.w);
    ((ushort4*)xb)[i] = o;
}

// transpose fp32 [K][Co] -> bf16 [Co][K].  Wq/Wk/Wv land contiguously.
__global__ void k_prep(const float* Wq, const float* Wk, const float* Wv, const float* Wo,
                       const float* Wf1, const float* Wf2,
                       unsigned short* Wqkvt, unsigned short* Wot,
                       unsigned short* Wf1t, unsigned short* Wf2t) {
    int z = blockIdx.y;
    const float* in; unsigned short* out; int K, Co;
    switch (z) {
        case 0: in = Wq;  out = Wqkvt;          K = 128; Co = 128; break;
        case 1: in = Wk;  out = Wqkvt + 16384;  K = 128; Co = 128; break;
        case 2: in = Wv;  out = Wqkvt + 32768;  K = 128; Co = 128; break;
        case 3: in = Wo;  out = Wot;            K = 128; Co = 128; break;
        case 4: in = Wf1; out = Wf1t;           K = 128; Co = 512; break;
        default: in = Wf2; out = Wf2t;          K = 512; Co = 128; break;
    }
    int idx = blockIdx.x * 256 + threadIdx.x;
    if (idx >= K * Co) return;
    int k = idx / Co, c = idx % Co;
    out[c * K + k] = f2bf(in[idx]);
}

// ----------------------- 128x128-tile MFMA GEMM ----------------------------
// Block: 128 rows (m0) x 128 cols (n0). 4 waves in 2x2; wave = 64x64 out.
// A bf16 [M][K] row-major; Bt bf16 [Cout][K]. BK=64, staged in LDS via
// global_load_lds(16B). LDS layout: tile[row][pos*8..], pos = chunk^(row&7).
// EPI 0: store bf16. EPI 1: +bias, gelu, store bf16.
// EPI 2 (Cout==128, grid.y==1): +bias+resid, LN over 128 cols, outf/outb.

template <int EPI>
__global__ __launch_bounds__(256) void k_gemm_big(
    const unsigned short* __restrict__ A, const unsigned short* __restrict__ Bt,
    const float* __restrict__ bias, const float* __restrict__ resid,
    const float* __restrict__ g, const float* __restrict__ b,
    float* __restrict__ outf, unsigned short* __restrict__ outb,
    int M, int K, int Cout) {
    __shared__ unsigned short As[128 * 64];
    __shared__ unsigned short Bs[128 * 64];
    __shared__ float pSum[2][128];
    __shared__ float pSq[2][128];

    int tid = threadIdx.x;
    int wid = tid >> 6, lane = tid & 63;
    int quad = lane >> 4, l16 = lane & 15;
    int wr = wid >> 1, wc = wid & 1;
    int m0 = blockIdx.x * 128;
    int n0 = blockIdx.y * 128;

    // staging addresses: thread t loads 16B: row j*32+(t>>3), global chunk
    // (t&7)^((t>>3)&7) -> LDS slot (j*256+t)*8 elems (lane-ordered).
    int srow = tid >> 3;                       // 0..31
    int gch = (tid & 7) ^ (srow & 7);
    const unsigned short* gA[4];
    const unsigned short* gB[4];
#pragma unroll
    for (int j = 0; j < 4; ++j) {
        int ra = m0 + j * 32 + srow; if (ra > M - 1) ra = M - 1;
        gA[j] = A + (size_t)ra * K + gch * 8;
        gB[j] = Bt + (size_t)(n0 + j * 32 + srow) * K + gch * 8;
    }

    f32x4 acc[4][4];
#pragma unroll
    for (int i = 0; i < 4; ++i)
#pragma unroll
        for (int j = 0; j < 4; ++j) acc[i][j] = {0.f, 0.f, 0.f, 0.f};

    int KT = K >> 6;
    for (int kt = 0; kt < KT; ++kt) {
        int ko = kt * 64;
#pragma unroll
        for (int j = 0; j < 4; ++j) {
            gload16(gA[j] + ko, As + j * 2048 + tid * 8);
            gload16(gB[j] + ko, Bs + j * 2048 + tid * 8);
        }
        __syncthreads();   // compiler drains vmcnt before s_barrier
#pragma unroll
        for (int s = 0; s < 2; ++s) {
            int swz = ((s * 4 + quad) ^ (l16 & 7)) * 8;
            bf16x8 af[4], bfr[4];
#pragma unroll
            for (int t4 = 0; t4 < 4; ++t4) {
                af[t4]  = *(const bf16x8*)&As[(wr * 64 + t4 * 16 + l16) * 64 + swz];
                bfr[t4] = *(const bf16x8*)&Bs[(wc * 64 + t4 * 16 + l16) * 64 + swz];
            }
#pragma unroll
            for (int ti = 0; ti < 4; ++ti)
#pragma unroll
                for (int tj = 0; tj < 4; ++tj)
                    acc[ti][tj] = __builtin_amdgcn_mfma_f32_16x16x32_bf16(
                        af[ti], bfr[tj], acc[ti][tj], 0, 0, 0);
        }
        __syncthreads();   // tile consumed before next stage overwrites
    }

    if constexpr (EPI != 2) {
#pragma unroll
        for (int ti = 0; ti < 4; ++ti)
#pragma unroll
            for (int tj = 0; tj < 4; ++tj) {
                int col = n0 + wc * 64 + tj * 16 + l16;
#pragma unroll
                for (int r = 0; r < 4; ++r) {
                    int row = m0 + wr * 64 + ti * 16 + quad * 4 + r;
                    if (row >= M) continue;
                    float v = acc[ti][tj][r];
                    if constexpr (EPI == 1) {
                        float gg = v + bias[col];
                        v = 0.5f * gg * (1.f + erff(gg * 0.70710678118f));
                    }
                    outb[(size_t)row * Cout + col] = f2bf(v);
                }
            }
    } else {
        // ---- fused bias + residual + LayerNorm over the 128 cols ----
        float bi[4], gv[4], bv[4];
#pragma unroll
        for (int tj = 0; tj < 4; ++tj) {
            int col = wc * 64 + tj * 16 + l16;
            bi[tj] = bias[col]; gv[tj] = g[col]; bv[tj] = b[col];
        }
#pragma unroll
        for (int ti = 0; ti < 4; ++ti)
#pragma unroll
            for (int tj = 0; tj < 4; ++tj) {
                int col = wc * 64 + tj * 16 + l16;
#pragma unroll
                for (int r = 0; r < 4; ++r) {
                    int row = m0 + wr * 64 + ti * 16 + quad * 4 + r;
                    float rv = (row < M) ? resid[(size_t)row * 128 + col] : 0.f;
                    acc[ti][tj][r] += bi[tj] + rv;
                }
            }
        // per-row partials: sum over tj in-register, over l16 via shfl_xor
#pragma unroll
        for (int ti = 0; ti < 4; ++ti)
#pragma unroll
            for (int r = 0; r < 4; ++r) {
                float s = acc[ti][0][r] + acc[ti][1][r] + acc[ti][2][r] + acc[ti][3][r];
                float q = acc[ti][0][r] * acc[ti][0][r] + acc[ti][1][r] * acc[ti][1][r]
                        + acc[ti][2][r] * acc[ti][2][r] + acc[ti][3][r] * acc[ti][3][r];
                s += __shfl_xor(s, 1); q += __shfl_xor(q, 1);
                s += __shfl_xor(s, 2); q += __shfl_xor(q, 2);
                s += __shfl_xor(s, 4); q += __shfl_xor(q, 4);
                s += __shfl_xor(s, 8); q += __shfl_xor(q, 8);
                if (l16 == 0) {
                    int lr = wr * 64 + ti * 16 + quad * 4 + r;
                    pSum[wc][lr] = s; pSq[wc][lr] = q;
                }
            }
        __syncthreads();
        if (tid < 128) {
            float s = pSum[0][tid] + pSum[1][tid];
            float q = pSq[0][tid] + pSq[1][tid];
            float mean = s * 0.0078125f;
            float var = q * 0.0078125f - mean * mean;
            pSum[0][tid] = mean;
            pSq[0][tid] = rsqrtf(var + 1e-5f);
        }
        __syncthreads();
#pragma unroll
        for (int ti = 0; ti < 4; ++ti)
#pragma unroll
            for (int r = 0; r < 4; ++r) {
                int lr = wr * 64 + ti * 16 + quad * 4 + r;
                int row = m0 + lr;
                if (row >= M) continue;
                float mean = pSum[0][lr], rs = pSq[0][lr];
#pragma unroll
                for (int tj = 0; tj < 4; ++tj) {
                    int col = wc * 64 + tj * 16 + l16;
                    float y = (acc[ti][tj][r] - mean) * rs * gv[tj] + bv[tj];
                    if (outf) outf[(size_t)row * 128 + col] = y;
                    if (outb) outb[(size_t)row * 128 + col] = f2bf(y);
                }
            }
    }
}

// ------------------------------ attention ----------------------------------
// One wave per destination node j; qkv row = [q|k|v] (192 dwords). Lane l
// owns channels (2l,2l+1); lanes 8h..8h+7 hold head h -> 3 shfl_xor reduce.
// 4-edge batches: 8 gathers in flight, one batched online-softmax update.

__global__ __launch_bounds__(256) void k_attn(
    const unsigned int* __restrict__ qkv, const int* __restrict__ nstart,
    const int* __restrict__ counts, const int* __restrict__ csr,
    unsigned int* __restrict__ ob, int N) {
    int j = blockIdx.x * 4 + (threadIdx.x >> 6);
    if (j >= N) return;
    int l = threadIdx.x & 63;

    unsigned int kw = qkv[(size_t)j * 192 + 64 + l];
    float kx = bflo(kw), ky = bfhi(kw);

    int start = nstart[j], cnt = counts[j];
    float m = -3.0e38f, lsum = 0.f, a0 = 0.f, a1 = 0.f;
    int i = 0;
    for (; i + 4 <= cnt; i += 4) {
        int r0 = csr[start + i + 0], r1 = csr[start + i + 1];
        int r2 = csr[start + i + 2], r3 = csr[start + i + 3];
        unsigned int qw0 = qkv[(size_t)r0 * 192 + l];
        unsigned int qw1 = qkv[(size_t)r1 * 192 + l];
        unsigned int qw2 = qkv[(size_t)r2 * 192 + l];
        unsigned int qw3 = qkv[(size_t)r3 * 192 + l];
        unsigned int vw0 = qkv[(size_t)r0 * 192 + 128 + l];
        unsigned int vw1 = qkv[(size_t)r1 * 192 + 128 + l];
        unsigned int vw2 = qkv[(size_t)r2 * 192 + 128 + l];
        unsigned int vw3 = qkv[(size_t)r3 * 192 + 128 + l];

        float p0 = fmaf(bflo(qw0), kx, bfhi(qw0) * ky);
        float p1 = fmaf(bflo(qw1), kx, bfhi(qw1) * ky);
        float p2 = fmaf(bflo(qw2), kx, bfhi(qw2) * ky);
        float p3 = fmaf(bflo(qw3), kx, bfhi(qw3) * ky);
        p0 += __shfl_xor(p0, 1); p1 += __shfl_xor(p1, 1);
        p2 += __shfl_xor(p2, 1); p3 += __shfl_xor(p3, 1);
        p0 += __shfl_xor(p0, 2); p1 += __shfl_xor(p1, 2);
        p2 += __shfl_xor(p2, 2); p3 += __shfl_xor(p3, 2);
        p0 += __shfl_xor(p0, 4); p1 += __shfl_xor(p1, 4);
        p2 += __shfl_xor(p2, 4); p3 += __shfl_xor(p3, 4);
        float s0 = p0 * 0.25f, s1 = p1 * 0.25f, s2 = p2 * 0.25f, s3 = p3 * 0.25f;

        float mn = fmaxf(fmaxf(fmaxf(s0, s1), fmaxf(s2, s3)), m);
        float scale = __expf(m - mn);
        float e0 = __expf(s0 - mn), e1 = __expf(s1 - mn);
        float e2 = __expf(s2 - mn), e3 = __expf(s3 - mn);
        lsum = lsum * scale + ((e0 + e1) + (e2 + e3));
        a0 = a0 * scale + e0 * bflo(vw0) + e1 * bflo(vw1) + e2 * bflo(vw2) + e3 * bflo(vw3);
        a1 = a1 * scale + e0 * bfhi(vw0) + e1 * bfhi(vw1) + e2 * bfhi(vw2) + e3 * bfhi(vw3);
        m = mn;
    }
    for (; i < cnt; ++i) {
        int r = csr[start + i];
        unsigned int qw = qkv[(size_t)r * 192 + l];
        unsigned int vw = qkv[(size_t)r * 192 + 128 + l];
        float p = fmaf(bflo(qw), kx, bfhi(qw) * ky);
        p += __shfl_xor(p, 1);
        p += __shfl_xor(p, 2);
        p += __shfl_xor(p, 4);
        float sc = p * 0.25f;
        float mn = fmaxf(m, sc);
        float scale = __expf(m - mn);
        float e = __expf(sc - mn);
        lsum = lsum * scale + e;
        a0 = a0 * scale + e * bflo(vw);
        a1 = a1 * scale + e * bfhi(vw);
        m = mn;
    }
    float inv = 1.f / (lsum + 1e-8f);
    unsigned int w = ((unsigned int)f2bf(a1 * inv) << 16) | (unsigned int)f2bf(a0 * inv);
    ob[(size_t)j * 64 + l] = w;
}

// -------------------------------- launch -----------------------------------

extern "C" void kernel_launch(void* const* d_in, const int* in_sizes, int n_in,
                              void* d_out, int out_size, void* d_ws, size_t ws_size,
                              hipStream_t stream) {
    const float* x   = (const float*)d_in[0];
    const int* ei    = (const int*)d_in[1];      // int64 materialized as int32
    const float* Wq  = (const float*)d_in[2];
    const float* Wk  = (const float*)d_in[3];
    const float* Wv  = (const float*)d_in[4];
    const float* Wo  = (const float*)d_in[5];
    const float* bo  = (const float*)d_in[6];
    const float* Wf1 = (const float*)d_in[7];
    const float* bf1 = (const float*)d_in[8];
    const float* Wf2 = (const float*)d_in[9];
    const float* bf2 = (const float*)d_in[10];
    const float* g1  = (const float*)d_in[11];
    const float* b1  = (const float*)d_in[12];
    const float* g2  = (const float*)d_in[13];
    const float* b2  = (const float*)d_in[14];

    int N = in_sizes[0] / 128;
    int E = in_sizes[1] / 2;
    int N2 = ((N + 127) / 128) * 128;
    int NE = E + N;

    char* p = (char*)d_ws;
    auto alloc = [&](size_t bytes) -> char* {
        char* r = p;
        p += (bytes + 255) & ~(size_t)255;
        return r;
    };
    // R0: [qkv (N2*384) | ob (N2*128)] bf16, reused as hb (N2*512) for FFN.
    unsigned short* qkv = (unsigned short*)alloc((size_t)N2 * 512 * 2);
    unsigned short* ob  = qkv + (size_t)N2 * 384;
    unsigned short* hb  = qkv;                   // alias (lifetime disjoint)
    // xb aliases x1b: xb dead after QKV GEMM; x1b first written by Wo-LN.
    unsigned short* x1b = (unsigned short*)alloc((size_t)N2 * 128 * 2);
    unsigned short* xb  = x1b;                   // alias
    float* x1f          = (float*)alloc((size_t)N2 * 128 * 4);
    unsigned short* Wqkvt = (unsigned short*)alloc(3 * 128 * 128 * 2);
    unsigned short* Wot   = (unsigned short*)alloc(128 * 128 * 2);
    unsigned short* Wf1t  = (unsigned short*)alloc(512 * 128 * 2);
    unsigned short* Wf2t  = (unsigned short*)alloc(128 * 512 * 2);
    int* counts = (int*)alloc((size_t)N * 4);
    int* incl   = (int*)alloc((size_t)N * 4);
    int* nstart = (int*)alloc((size_t)N * 4);
    int* cursor = (int*)alloc((size_t)N * 4);
    int* bsums  = (int*)alloc(1024 * 4);
    int* boffs  = (int*)alloc(1024 * 4);
    int* csr    = (int*)alloc((size_t)NE * 4);

    int NB = (N + 255) / 256;          // 196 (<256, one-block scan2)
    int M128 = (N + 127) / 128;        // 391

    k_zero<<<NB, 256, 0, stream>>>(counts, N);
    k_count<<<(NE + 255) / 256, 256, 0, stream>>>(ei, counts, E, N);
    k_scan1<<<NB, 256, 0, stream>>>(counts, incl, bsums, N);
    k_scan2<<<1, 256, 0, stream>>>(bsums, boffs, NB);
    k_scan3<<<NB, 256, 0, stream>>>(incl, counts, boffs, nstart, cursor, N);
    k_fill<<<(NE + 255) / 256, 256, 0, stream>>>(ei, cursor, csr, E, N);

    k_cast<<<((N * 128 / 4) + 255) / 256, 256, 0, stream>>>(x, xb, N * 128 / 4);
    k_prep<<<dim3(256, 6), 256, 0, stream>>>(Wq, Wk, Wv, Wo, Wf1, Wf2,
                                             Wqkvt, Wot, Wf1t, Wf2t);

    // QKV: A=xb [N][128], Bt=Wqkvt [384][128] -> qkv [N][384]
    k_gemm_big<0><<<dim3(M128, 3), 256, 0, stream>>>(
        xb, Wqkvt, nullptr, nullptr, nullptr, nullptr, nullptr, qkv, N, 128, 384);

    k_attn<<<(N + 3) / 4, 256, 0, stream>>>((const unsigned int*)qkv, nstart,
                                            counts, csr, (unsigned int*)ob, N);

    // Wo + bias + residual(x) + LN1 -> x1f (fp32), x1b (bf16)
    k_gemm_big<2><<<dim3(M128, 1), 256, 0, stream>>>(
        ob, Wot, bo, x, g1, b1, x1f, x1b, N, 128, 128);

    // FFN1 + gelu -> hb (aliases qkv|ob, both dead)
    k_gemm_big<1><<<dim3(M128, 4), 256, 0, stream>>>(
        x1b, Wf1t, bf1, nullptr, nullptr, nullptr, nullptr, hb, N, 128, 512);

    // FFN2 + bias + residual(x1f) + LN2 -> d_out (fp32)
    k_gemm_big<2><<<dim3(M128, 1), 256, 0, stream>>>(
        hb, Wf2t, bf2, x1f, g2, b2, (float*)d_out, nullptr, N, 512, 128);
}